// Round 5
// baseline (724.559 us; speedup 1.0000x reference)
//
#include <hip/hip_runtime.h>
#include <math.h>

#define EPSBN 1e-5f

typedef __attribute__((ext_vector_type(8))) short short8;
typedef __attribute__((ext_vector_type(8))) _Float16 f16x8;
typedef __attribute__((ext_vector_type(2))) _Float16 h2;
typedef __attribute__((ext_vector_type(4))) float f32x4;

#if defined(__has_builtin)
#if __has_builtin(__builtin_amdgcn_fdot2)
#define HAVE_FDOT2 1
#endif
#endif

__device__ __forceinline__ unsigned short f2h(float f) {
  _Float16 h = (_Float16)f;
  return __builtin_bit_cast(unsigned short, h);
}
__device__ __forceinline__ h2 bch(unsigned u) { return __builtin_bit_cast(h2, u); }
__device__ __forceinline__ unsigned h2u(h2 v) { return __builtin_bit_cast(unsigned, v); }
// LDS XOR swizzle (involution on byte bits 4-5 <- bits 7-8) -> 2 lanes/bank
__device__ __forceinline__ int swz(int b) { return b ^ (((b >> 7) & 3) << 4); }

// ---------------------------------------------------------------------------
// dual GEMM: C[M,512] = A[M,256] @ [Wl | Wr]  (f16 in, f32 acc, f16 out)
// Wt pre-transposed: Wt[n][k]. 128x128 tile, 4 waves, BK=32, f16 MFMA.
// ---------------------------------------------------------------------------
__global__ __launch_bounds__(256) void gemm_dual(const unsigned short* __restrict__ Ab,
                                                 const unsigned short* __restrict__ Wt,
                                                 unsigned short* __restrict__ C, int M) {
  __shared__ __align__(16) short As[4096];  // 8KB [128][32] f16, swizzled
  __shared__ __align__(16) short Bs[4096];
  const int tid = threadIdx.x;
  const int lane = tid & 63, w = tid >> 6;
  const int wr = w >> 1, wc = w & 1;
  const int bm = blockIdx.x * 128, bn = blockIdx.y * 128;

  const int srow = tid >> 2;
  const int scol = (tid & 3) << 4;
  const char* gA = (const char*)Ab + (size_t)(bm + srow) * 512 + scol;
  const char* gB = (const char*)Wt + (size_t)(bn + srow) * 512 + scol;
  char* wA0 = (char*)As + swz(tid * 16);
  char* wA1 = (char*)As + swz((256 + tid) * 16);
  char* wB0 = (char*)Bs + swz(tid * 16);
  char* wB1 = (char*)Bs + swz((256 + tid) * 16);

  int aoff[4], boff[4];
#pragma unroll
  for (int i = 0; i < 4; ++i) {
    aoff[i] = swz(((wr * 64 + i * 16 + (lane & 15)) << 6) + ((lane >> 4) << 4));
    boff[i] = swz(((wc * 64 + i * 16 + (lane & 15)) << 6) + ((lane >> 4) << 4));
  }

  f32x4 acc[4][4] = {};
  short8 ra0 = *(const short8*)(gA);
  short8 ra1 = *(const short8*)(gA + 64 * 512);
  short8 rb0 = *(const short8*)(gB);
  short8 rb1 = *(const short8*)(gB + 64 * 512);

  for (int ks = 0; ks < 8; ++ks) {
    *(short8*)wA0 = ra0; *(short8*)wA1 = ra1;
    *(short8*)wB0 = rb0; *(short8*)wB1 = rb1;
    __syncthreads();
    if (ks < 7) {
      int off = (ks + 1) * 64;
      ra0 = *(const short8*)(gA + off);
      ra1 = *(const short8*)(gA + 64 * 512 + off);
      rb0 = *(const short8*)(gB + off);
      rb1 = *(const short8*)(gB + 64 * 512 + off);
    }
    short8 af[4], bfr[4];
#pragma unroll
    for (int i = 0; i < 4; ++i) af[i] = *(const short8*)((const char*)As + aoff[i]);
#pragma unroll
    for (int i = 0; i < 4; ++i) bfr[i] = *(const short8*)((const char*)Bs + boff[i]);
#pragma unroll
    for (int mr = 0; mr < 4; ++mr)
#pragma unroll
      for (int nc = 0; nc < 4; ++nc)
        acc[mr][nc] = __builtin_amdgcn_mfma_f32_16x16x32_f16(
            __builtin_bit_cast(f16x8, af[mr]), __builtin_bit_cast(f16x8, bfr[nc]),
            acc[mr][nc], 0, 0, 0);
    __syncthreads();
  }

#pragma unroll
  for (int mr = 0; mr < 4; ++mr) {
#pragma unroll
    for (int j = 0; j < 4; ++j) {
      int row = bm + wr * 64 + mr * 16 + (lane >> 4) * 4 + j;
      if (row < M) {
#pragma unroll
        for (int nc = 0; nc < 4; ++nc) {
          int col = bn + wc * 64 + nc * 16 + (lane & 15);
          C[(size_t)row * 512 + col] = f2h(acc[mr][nc][j]);
        }
      }
    }
  }
}

// ---------------------------------------------------------------------------
// prep: f32->f16 convert of x, Wt1/Wt2 build (transpose+cvt), dst histogram
// ---------------------------------------------------------------------------
__global__ void prep(const float* __restrict__ x, const float* __restrict__ W1l,
                     const float* __restrict__ W1r, const float* __restrict__ W2l,
                     const float* __restrict__ W2r, const int* __restrict__ ei,
                     unsigned short* __restrict__ xh, unsigned short* __restrict__ Wt1,
                     unsigned short* __restrict__ Wt2, int* __restrict__ cnt,
                     int n4x, int Etot, int E) {
  int t = blockIdx.x * 256 + threadIdx.x;
  if (t < n4x) {  // x -> f16, 4/thread
    float4 v = *(const float4*)&x[(size_t)t * 4];
    ushort4 o;
    o.x = f2h(v.x); o.y = f2h(v.y); o.z = f2h(v.z); o.w = f2h(v.w);
    *(ushort4*)&xh[(size_t)t * 4] = o;
    return;
  }
  t -= n4x;
  if (t < 131072) {  // Wt1[n][k]
    int n = t >> 8, k = t & 255;
    const float* W = (n < 256) ? W1l : W1r;
    Wt1[t] = f2h(W[k * 256 + (n & 255)]);
    return;
  }
  t -= 131072;
  if (t < 131072) {
    int n = t >> 8, k = t & 255;
    const float* W = (n < 256) ? W2l : W2r;
    Wt2[t] = f2h(W[k * 256 + (n & 255)]);
    return;
  }
  t -= 131072;
  if (t < Etot) {
    int d = (t < E) ? ei[E + t] : t - E;
    atomicAdd(&cnt[d], 1);
  }
}

__global__ __launch_bounds__(1024) void scan_block(const int* __restrict__ cnt,
                                                   int* __restrict__ rowptr,
                                                   int N, int Etot) {
  __shared__ int lds[1024];
  int t = threadIdx.x;
  int strip = (N + 1023) >> 10;
  int lo = t * strip, hi = min(lo + strip, N);
  int s = 0;
  for (int i = lo; i < hi && lo < N; ++i) s += cnt[i];
  lds[t] = s;
  __syncthreads();
  for (int off = 1; off < 1024; off <<= 1) {
    int v = (t >= off) ? lds[t - off] : 0;
    __syncthreads();
    lds[t] += v;
    __syncthreads();
  }
  int base = lds[t] - s;
  for (int i = lo; i < hi && lo < N; ++i) { rowptr[i] = base; base += cnt[i]; }
  if (t == 1023) rowptr[N] = Etot;
}

__global__ void scatter_src(const int* __restrict__ ei, const int* __restrict__ rowptr,
                            int* __restrict__ cur, int* __restrict__ srcs,
                            int Etot, int E) {
  int e = blockIdx.x * 256 + threadIdx.x;
  if (e >= Etot) return;
  int s, d;
  if (e < E) { s = ei[e]; d = ei[E + e]; } else { s = e - E; d = s; }
  int pos = rowptr[d] + atomicAdd(&cur[d], 1);
  srcs[pos] = s;
}

// ---------------------------------------------------------------------------
// Fused GATv2: one wave per dst, raw-exp softmax (scores bounded), f16 gathers.
// xlr[N][512] f16: cols 0..255 xl, 256..511 xr. lane l -> head l>>4, ch l*4..+3
// leaky_relu(x) = 0.6x + 0.4|x|;  score = e.(0.6w) + |e|.(0.4w)
// CONCAT=1: write f16 [N,256]+bias.  CONCAT=0: head-mean -> f32 [N,64]+bias.
// ---------------------------------------------------------------------------
template <int CONCAT>
__global__ __launch_bounds__(256) void gat_fused(const unsigned short* __restrict__ xlr,
                                                 const float* __restrict__ att,
                                                 const float* __restrict__ bias,
                                                 const int* __restrict__ rowptr,
                                                 const int* __restrict__ srcs,
                                                 void* __restrict__ outv, int N) {
  int d = (blockIdx.x << 2) + (threadIdx.x >> 6);
  if (d >= N) return;
  int lane = threadIdx.x & 63;
  uint2 ub = *(const uint2*)&xlr[(size_t)d * 512 + 256 + lane * 4];
  h2 xb01 = bch(ub.x), xb23 = bch(ub.y);
  float4 wf = *(const float4*)&att[lane * 4];  // (l>>4)*64+(l&15)*4 == l*4
  h2 w06a = {(_Float16)(0.6f * wf.x), (_Float16)(0.6f * wf.y)};
  h2 w06b = {(_Float16)(0.6f * wf.z), (_Float16)(0.6f * wf.w)};
  h2 w04a = {(_Float16)(0.4f * wf.x), (_Float16)(0.4f * wf.y)};
  h2 w04b = {(_Float16)(0.4f * wf.z), (_Float16)(0.4f * wf.w)};
  int i = rowptr[d], end = rowptr[d + 1];
  float den = 0.f, a0 = 0.f, a1 = 0.f, a2 = 0.f, a3 = 0.f;
  int s0 = srcs[i];
  uint2 ua = *(const uint2*)&xlr[(size_t)s0 * 512 + lane * 4];
  for (; i < end; ++i) {
    uint2 cur = ua;
    if (i + 1 < end) {
      int sn = srcs[i + 1];
      ua = *(const uint2*)&xlr[(size_t)sn * 512 + lane * 4];
    }
    h2 c01 = bch(cur.x), c23 = bch(cur.y);
    h2 e01 = c01 + xb01, e23 = c23 + xb23;
    h2 ab01 = bch(h2u(e01) & 0x7FFF7FFFu);
    h2 ab23 = bch(h2u(e23) & 0x7FFF7FFFu);
    float p;
#ifdef HAVE_FDOT2
    p = __builtin_amdgcn_fdot2(ab01, w04a,
        __builtin_amdgcn_fdot2(ab23, w04b,
        __builtin_amdgcn_fdot2(e01, w06a,
        __builtin_amdgcn_fdot2(e23, w06b, 0.f, false), false), false), false);
#else
    {
      float e0 = (float)e01.x, e1 = (float)e01.y, e2 = (float)e23.x, e3 = (float)e23.y;
      float l0 = fmaxf(e0, 0.2f * e0), l1 = fmaxf(e1, 0.2f * e1);
      float l2 = fmaxf(e2, 0.2f * e2), l3 = fmaxf(e3, 0.2f * e3);
      p = l0 * wf.x + l1 * wf.y + l2 * wf.z + l3 * wf.w;
    }
#endif
    p += __shfl_xor(p, 1);
    p += __shfl_xor(p, 2);
    p += __shfl_xor(p, 4);
    p += __shfl_xor(p, 8);
    float ex = __expf(p);
    float vx = (float)c01.x, vy = (float)c01.y, vz = (float)c23.x, vw = (float)c23.y;
    den += ex;
    a0 = fmaf(ex, vx, a0);
    a1 = fmaf(ex, vy, a1);
    a2 = fmaf(ex, vz, a2);
    a3 = fmaf(ex, vw, a3);
  }
  float inv = 1.f / den;
  if (CONCAT) {
    float4 bb = *(const float4*)&bias[lane * 4];
    ushort4 o;
    o.x = f2h(a0 * inv + bb.x); o.y = f2h(a1 * inv + bb.y);
    o.z = f2h(a2 * inv + bb.z); o.w = f2h(a3 * inv + bb.w);
    *(ushort4*)&((unsigned short*)outv)[(size_t)d * 256 + lane * 4] = o;
  } else {
    float v0 = a0 * inv, v1 = a1 * inv, v2 = a2 * inv, v3 = a3 * inv;
    v0 += __shfl_xor(v0, 16); v0 += __shfl_xor(v0, 32);
    v1 += __shfl_xor(v1, 16); v1 += __shfl_xor(v1, 32);
    v2 += __shfl_xor(v2, 16); v2 += __shfl_xor(v2, 32);
    v3 += __shfl_xor(v3, 16); v3 += __shfl_xor(v3, 32);
    if (lane < 16) {
      float4 bb = *(const float4*)&bias[lane * 4];
      *(float4*)&((float*)outv)[(size_t)d * 64 + lane * 4] =
          make_float4(0.25f * v0 + bb.x, 0.25f * v1 + bb.y,
                      0.25f * v2 + bb.z, 0.25f * v3 + bb.w);
    }
  }
}

// column sums/sumsq over h[N,256] f16, LDS-reduced, 8 atomics per 64 lanes
__global__ __launch_bounds__(256) void bn_stats(const unsigned short* __restrict__ h,
                                                float* __restrict__ sums, int N) {
  __shared__ float4 rs[4][64], rq[4][64];
  int lane = threadIdx.x & 63;
  int rg = threadIdx.x >> 6;
  int c4 = lane * 4;
  float s0 = 0, s1 = 0, s2 = 0, s3 = 0, q0 = 0, q1 = 0, q2 = 0, q3 = 0;
  for (int r = blockIdx.x * 4 + rg; r < N; r += gridDim.x * 4) {
    uint2 v = *(const uint2*)&h[(size_t)r * 256 + c4];
    h2 a = bch(v.x), b = bch(v.y);
    float f0 = (float)a.x, f1 = (float)a.y, f2 = (float)b.x, f3 = (float)b.y;
    s0 += f0; q0 += f0 * f0;
    s1 += f1; q1 += f1 * f1;
    s2 += f2; q2 += f2 * f2;
    s3 += f3; q3 += f3 * f3;
  }
  rs[rg][lane] = make_float4(s0, s1, s2, s3);
  rq[rg][lane] = make_float4(q0, q1, q2, q3);
  __syncthreads();
  if (rg == 0) {
    float4 S = rs[0][lane], Q = rq[0][lane];
#pragma unroll
    for (int g = 1; g < 4; ++g) {
      float4 t = rs[g][lane]; S.x += t.x; S.y += t.y; S.z += t.z; S.w += t.w;
      float4 u = rq[g][lane]; Q.x += u.x; Q.y += u.y; Q.z += u.z; Q.w += u.w;
    }
    atomicAdd(&sums[c4 + 0], S.x); atomicAdd(&sums[c4 + 1], S.y);
    atomicAdd(&sums[c4 + 2], S.z); atomicAdd(&sums[c4 + 3], S.w);
    atomicAdd(&sums[256 + c4 + 0], Q.x); atomicAdd(&sums[256 + c4 + 1], Q.y);
    atomicAdd(&sums[256 + c4 + 2], Q.z); atomicAdd(&sums[256 + c4 + 3], Q.w);
  }
}

// per-channel scale/shift from sums
__global__ void bn_coef(const float* __restrict__ sums, const float* __restrict__ g,
                        const float* __restrict__ be, float* __restrict__ coef, int N) {
  int c = threadIdx.x;
  float inv_n = 1.f / (float)N;
  float mu = sums[c] * inv_n;
  float var = sums[256 + c] * inv_n - mu * mu;
  float sc = g[c] * rsqrtf(var + EPSBN);
  coef[c] = sc;
  coef[256 + c] = be[c] - mu * sc;
}

// h = relu(h*scale+shift), f16 in-place
__global__ void bn_apply_relu(unsigned short* __restrict__ h, const float* __restrict__ coef,
                              int N) {
  int i = blockIdx.x * 256 + threadIdx.x;
  if (i >= N * 64) return;
  int base = i * 4, c = base & 255;
  uint2 v = *(const uint2*)&h[base];
  h2 a = bch(v.x), b = bch(v.y);
  float4 sc = *(const float4*)&coef[c];
  float4 sh = *(const float4*)&coef[256 + c];
  float r0 = fmaf((float)a.x, sc.x, sh.x); r0 = r0 > 0.f ? r0 : 0.f;
  float r1 = fmaf((float)a.y, sc.y, sh.y); r1 = r1 > 0.f ? r1 : 0.f;
  float r2 = fmaf((float)b.x, sc.z, sh.z); r2 = r2 > 0.f ? r2 : 0.f;
  float r3 = fmaf((float)b.y, sc.w, sh.w); r3 = r3 > 0.f ? r3 : 0.f;
  ushort4 o;
  o.x = f2h(r0); o.y = f2h(r1); o.z = f2h(r2); o.w = f2h(r3);
  *(ushort4*)&h[base] = o;
}

// column stats over o[:, :32] f32
__global__ void bn2_stats(const float* __restrict__ o, float* __restrict__ sums, int N) {
  int c = threadIdx.x & 31;
  int rr = threadIdx.x >> 5;
  float s = 0.f, s2 = 0.f;
  for (int r = blockIdx.x * 8 + rr; r < N; r += gridDim.x * 8) {
    float v = o[((size_t)r << 6) + c];
    s += v; s2 += v * v;
  }
  atomicAdd(&sums[c], s);
  atomicAdd(&sums[32 + c], s2);
}

__global__ void write_out(const float* __restrict__ o, const float* __restrict__ sums,
                          float* __restrict__ out, int N) {
  int i = blockIdx.x * blockDim.x + threadIdx.x;
  if (i >= N * 32) return;
  int n = i >> 5, c = i & 31;
  float inv_n = 1.f / (float)N;
  float mu = sums[c] * inv_n;
  float var = sums[32 + c] * inv_n - mu * mu;
  out[i] = (o[((size_t)n << 6) + c] - mu) * rsqrtf(var + EPSBN);
  float t = o[((size_t)n << 6) + 32 + c];
  out[(size_t)N * 32 + i] = 1.f / (1.f + __expf(-t));
}

extern "C" void kernel_launch(void* const* d_in, const int* in_sizes, int n_in,
                              void* d_out, int out_size, void* d_ws, size_t ws_size,
                              hipStream_t stream) {
  const float* x    = (const float*)d_in[0];
  const int*   ei   = (const int*)d_in[1];
  const float* W1l  = (const float*)d_in[2];
  const float* W1r  = (const float*)d_in[3];
  const float* att1 = (const float*)d_in[4];
  const float* b1   = (const float*)d_in[5];
  const float* g1   = (const float*)d_in[6];
  const float* be1  = (const float*)d_in[7];
  const float* W2l  = (const float*)d_in[8];
  const float* W2r  = (const float*)d_in[9];
  const float* att2 = (const float*)d_in[10];
  const float* b2   = (const float*)d_in[11];
  float* out = (float*)d_out;

  const int N = in_sizes[0] / 256;   // 50000
  const int E = in_sizes[1] / 2;     // 800000
  const int Etot = E + N;
  const int Npad = ((N + 127) / 128) * 128;

  char* ws = (char*)d_ws;
  unsigned short* xh  = (unsigned short*)ws; ws += (size_t)Npad * 256 * 2;  // x f16
  unsigned short* hb  = (unsigned short*)ws; ws += (size_t)Npad * 256 * 2;  // h1 f16
  unsigned short* AB  = (unsigned short*)ws; ws += (size_t)Npad * 512 * 2;  // [xl|xr] f16
  unsigned short* Wt1 = (unsigned short*)ws; ws += (size_t)512 * 256 * 2;
  unsigned short* Wt2 = (unsigned short*)ws; ws += (size_t)512 * 256 * 2;
  float* o    = (float*)ws;  ws += (size_t)N * 64 * 4;
  int* rowptr = (int*)ws;    ws += (size_t)(N + 1) * 4;
  int* cnt    = (int*)ws;    ws += (size_t)N * 4;
  int* srcs   = (int*)ws;    ws += (size_t)Etot * 4;
  float* sums1 = (float*)ws; ws += 512 * 4;
  float* sums2 = (float*)ws; ws += 64 * 4;
  float* coef1 = (float*)ws; ws += 512 * 4;

  dim3 gemmGrid(Npad / 128, 4);
  int dstBlocks = (N + 3) / 4;
  int n4x = N * 64;
  int prepTotal = n4x + 131072 + 131072 + Etot;

  hipMemsetAsync(cnt, 0, (size_t)N * 4, stream);
  hipMemsetAsync(sums1, 0, 512 * 4, stream);
  hipMemsetAsync(sums2, 0, 64 * 4, stream);
  prep<<<(prepTotal + 255) / 256, 256, 0, stream>>>(x, W1l, W1r, W2l, W2r, ei,
                                                    xh, Wt1, Wt2, cnt, n4x, Etot, E);
  scan_block<<<1, 1024, 0, stream>>>(cnt, rowptr, N, Etot);
  hipMemsetAsync(cnt, 0, (size_t)N * 4, stream);
  scatter_src<<<(Etot + 255) / 256, 256, 0, stream>>>(ei, rowptr, cnt, srcs, Etot, E);

  // ---- conv1 ----
  gemm_dual<<<gemmGrid, 256, 0, stream>>>(xh, Wt1, AB, N);
  gat_fused<1><<<dstBlocks, 256, 0, stream>>>(AB, att1, b1, rowptr, srcs, hb, N);
  bn_stats<<<512, 256, 0, stream>>>(hb, sums1, N);
  bn_coef<<<1, 256, 0, stream>>>(sums1, g1, be1, coef1, N);
  bn_apply_relu<<<(N * 64 + 255) / 256, 256, 0, stream>>>(hb, coef1, N);

  // ---- conv2 ----
  gemm_dual<<<gemmGrid, 256, 0, stream>>>(hb, Wt2, AB, N);
  gat_fused<0><<<dstBlocks, 256, 0, stream>>>(AB, att2, b2, rowptr, srcs, o, N);
  bn2_stats<<<128, 256, 0, stream>>>(o, sums2, N);
  write_out<<<(N * 32 + 255) / 256, 256, 0, stream>>>(o, sums2, out, N);
}

// Round 6
// 610.356 us; speedup vs baseline: 1.1871x; 1.1871x over previous
//
#include <hip/hip_runtime.h>
#include <math.h>

#define EPSBN 1e-5f

typedef __attribute__((ext_vector_type(8))) short short8;
typedef __attribute__((ext_vector_type(8))) _Float16 f16x8;
typedef __attribute__((ext_vector_type(2))) _Float16 h2;
typedef __attribute__((ext_vector_type(4))) float f32x4;

#if defined(__has_builtin)
#if __has_builtin(__builtin_amdgcn_fdot2)
#define HAVE_FDOT2 1
#endif
#endif

__device__ __forceinline__ unsigned short f2h(float f) {
  _Float16 h = (_Float16)f;
  return __builtin_bit_cast(unsigned short, h);
}
__device__ __forceinline__ h2 bch(unsigned u) { return __builtin_bit_cast(h2, u); }
__device__ __forceinline__ unsigned h2u(h2 v) { return __builtin_bit_cast(unsigned, v); }
// LDS XOR swizzle (involution on byte bits 4-5 <- bits 7-8) -> 2 lanes/bank
__device__ __forceinline__ int swz(int b) { return b ^ (((b >> 7) & 3) << 4); }

// ---------------------------------------------------------------------------
// dual GEMM: C[M,512] = A[M,256] @ [Wl | Wr]  (f16 in, f32 acc, f16 out)
// Wt pre-transposed: Wt[n][k]. 128x128 tile, 4 waves, BK=32, f16 MFMA.
// Swapped-operand MFMA (mfma(B,A) -> D^T): thread's 4 acc elems = 4 consecutive
// cols of one row -> ushort4 packed 8B stores (vs 64x 2B scatter).
// ---------------------------------------------------------------------------
__global__ __launch_bounds__(256) void gemm_dual(const unsigned short* __restrict__ Ab,
                                                 const unsigned short* __restrict__ Wt,
                                                 unsigned short* __restrict__ C, int M) {
  __shared__ __align__(16) short As[4096];  // 8KB [128][32] f16, swizzled
  __shared__ __align__(16) short Bs[4096];
  const int tid = threadIdx.x;
  const int lane = tid & 63, w = tid >> 6;
  const int wr = w >> 1, wc = w & 1;
  const int bm = blockIdx.x * 128, bn = blockIdx.y * 128;

  const int srow = tid >> 2;
  const int scol = (tid & 3) << 4;
  const char* gA = (const char*)Ab + (size_t)(bm + srow) * 512 + scol;
  const char* gB = (const char*)Wt + (size_t)(bn + srow) * 512 + scol;
  char* wA0 = (char*)As + swz(tid * 16);
  char* wA1 = (char*)As + swz((256 + tid) * 16);
  char* wB0 = (char*)Bs + swz(tid * 16);
  char* wB1 = (char*)Bs + swz((256 + tid) * 16);

  int aoff[4], boff[4];
#pragma unroll
  for (int i = 0; i < 4; ++i) {
    aoff[i] = swz(((wr * 64 + i * 16 + (lane & 15)) << 6) + ((lane >> 4) << 4));
    boff[i] = swz(((wc * 64 + i * 16 + (lane & 15)) << 6) + ((lane >> 4) << 4));
  }

  f32x4 acc[4][4] = {};
  short8 ra0 = *(const short8*)(gA);
  short8 ra1 = *(const short8*)(gA + 64 * 512);
  short8 rb0 = *(const short8*)(gB);
  short8 rb1 = *(const short8*)(gB + 64 * 512);

  for (int ks = 0; ks < 8; ++ks) {
    *(short8*)wA0 = ra0; *(short8*)wA1 = ra1;
    *(short8*)wB0 = rb0; *(short8*)wB1 = rb1;
    __syncthreads();
    if (ks < 7) {
      int off = (ks + 1) * 64;
      ra0 = *(const short8*)(gA + off);
      ra1 = *(const short8*)(gA + 64 * 512 + off);
      rb0 = *(const short8*)(gB + off);
      rb1 = *(const short8*)(gB + 64 * 512 + off);
    }
    short8 af[4], bfr[4];
#pragma unroll
    for (int i = 0; i < 4; ++i) af[i] = *(const short8*)((const char*)As + aoff[i]);
#pragma unroll
    for (int i = 0; i < 4; ++i) bfr[i] = *(const short8*)((const char*)Bs + boff[i]);
#pragma unroll
    for (int mr = 0; mr < 4; ++mr)
#pragma unroll
      for (int nc = 0; nc < 4; ++nc)
        acc[mr][nc] = __builtin_amdgcn_mfma_f32_16x16x32_f16(
            __builtin_bit_cast(f16x8, bfr[nc]), __builtin_bit_cast(f16x8, af[mr]),
            acc[mr][nc], 0, 0, 0);  // swapped: D^T layout
    __syncthreads();
  }

  // D^T: row = lane&15 (+m base), col = (lane>>4)*4 + j (+n base)
#pragma unroll
  for (int mr = 0; mr < 4; ++mr) {
    int row = bm + wr * 64 + mr * 16 + (lane & 15);
    if (row < M) {
#pragma unroll
      for (int nc = 0; nc < 4; ++nc) {
        int col = bn + wc * 64 + nc * 16 + ((lane >> 4) << 2);
        ushort4 o;
        o.x = f2h(acc[mr][nc][0]); o.y = f2h(acc[mr][nc][1]);
        o.z = f2h(acc[mr][nc][2]); o.w = f2h(acc[mr][nc][3]);
        *(ushort4*)&C[(size_t)row * 512 + col] = o;
      }
    }
  }
}

// ---------------------------------------------------------------------------
// prep: f32->f16 convert of x, Wt1/Wt2 build (transpose+cvt), dst histogram
// ---------------------------------------------------------------------------
__global__ void prep(const float* __restrict__ x, const float* __restrict__ W1l,
                     const float* __restrict__ W1r, const float* __restrict__ W2l,
                     const float* __restrict__ W2r, const int* __restrict__ ei,
                     unsigned short* __restrict__ xh, unsigned short* __restrict__ Wt1,
                     unsigned short* __restrict__ Wt2, int* __restrict__ cnt,
                     int n4x, int Etot, int E) {
  int t = blockIdx.x * 256 + threadIdx.x;
  if (t < n4x) {
    float4 v = *(const float4*)&x[(size_t)t * 4];
    ushort4 o;
    o.x = f2h(v.x); o.y = f2h(v.y); o.z = f2h(v.z); o.w = f2h(v.w);
    *(ushort4*)&xh[(size_t)t * 4] = o;
    return;
  }
  t -= n4x;
  if (t < 131072) {
    int n = t >> 8, k = t & 255;
    const float* W = (n < 256) ? W1l : W1r;
    Wt1[t] = f2h(W[k * 256 + (n & 255)]);
    return;
  }
  t -= 131072;
  if (t < 131072) {
    int n = t >> 8, k = t & 255;
    const float* W = (n < 256) ? W2l : W2r;
    Wt2[t] = f2h(W[k * 256 + (n & 255)]);
    return;
  }
  t -= 131072;
  if (t < Etot) {
    int d = (t < E) ? ei[E + t] : t - E;
    atomicAdd(&cnt[d], 1);
  }
}

__global__ __launch_bounds__(1024) void scan_block(const int* __restrict__ cnt,
                                                   int* __restrict__ rowptr,
                                                   int N, int Etot) {
  __shared__ int lds[1024];
  int t = threadIdx.x;
  int strip = (N + 1023) >> 10;
  int lo = t * strip, hi = min(lo + strip, N);
  int s = 0;
  for (int i = lo; i < hi && lo < N; ++i) s += cnt[i];
  lds[t] = s;
  __syncthreads();
  for (int off = 1; off < 1024; off <<= 1) {
    int v = (t >= off) ? lds[t - off] : 0;
    __syncthreads();
    lds[t] += v;
    __syncthreads();
  }
  int base = lds[t] - s;
  for (int i = lo; i < hi && lo < N; ++i) { rowptr[i] = base; base += cnt[i]; }
  if (t == 1023) rowptr[N] = Etot;
}

__global__ void scatter_src(const int* __restrict__ ei, const int* __restrict__ rowptr,
                            int* __restrict__ cur, int* __restrict__ srcs,
                            int Etot, int E) {
  int e = blockIdx.x * 256 + threadIdx.x;
  if (e >= Etot) return;
  int s, d;
  if (e < E) { s = ei[e]; d = ei[E + e]; } else { s = e - E; d = s; }
  int pos = rowptr[d] + atomicAdd(&cur[d], 1);
  srcs[pos] = s;
}

// ---------------------------------------------------------------------------
// Fused GATv2: one wave per dst, raw-exp softmax (scores bounded), f16 gathers,
// 4-deep edge prefetch pipeline (gather latency hiding).
// xlr[N][512] f16: cols 0..255 xl, 256..511 xr. lane l -> head l>>4, ch l*4..+3
// leaky_relu(x) = 0.6x + 0.4|x|;  score = e.(0.6w) + |e|.(0.4w)
// ---------------------------------------------------------------------------
template <int CONCAT>
__global__ __launch_bounds__(256) void gat_fused(const unsigned short* __restrict__ xlr,
                                                 const float* __restrict__ att,
                                                 const float* __restrict__ bias,
                                                 const int* __restrict__ rowptr,
                                                 const int* __restrict__ srcs,
                                                 void* __restrict__ outv, int N) {
  int d = (blockIdx.x << 2) + (threadIdx.x >> 6);
  if (d >= N) return;
  int lane = threadIdx.x & 63;
  uint2 ub = *(const uint2*)&xlr[(size_t)d * 512 + 256 + lane * 4];
  h2 xb01 = bch(ub.x), xb23 = bch(ub.y);
  float4 wf = *(const float4*)&att[lane * 4];  // (l>>4)*64+(l&15)*4 == l*4
  h2 w06a = {(_Float16)(0.6f * wf.x), (_Float16)(0.6f * wf.y)};
  h2 w06b = {(_Float16)(0.6f * wf.z), (_Float16)(0.6f * wf.w)};
  h2 w04a = {(_Float16)(0.4f * wf.x), (_Float16)(0.4f * wf.y)};
  h2 w04b = {(_Float16)(0.4f * wf.z), (_Float16)(0.4f * wf.w)};
  int i0 = rowptr[d], end = rowptr[d + 1];
  int eM1 = end - 1;
  float den = 0.f, a0 = 0.f, a1 = 0.f, a2 = 0.f, a3 = 0.f;

  auto GLD = [&](int j) -> uint2 {
    int jj = min(j, eM1);
    return *(const uint2*)&xlr[(size_t)srcs[jj] * 512 + lane * 4];
  };
  auto PROC = [&](uint2 cur) {
    h2 c01 = bch(cur.x), c23 = bch(cur.y);
    h2 e01 = c01 + xb01, e23 = c23 + xb23;
    float p;
#ifdef HAVE_FDOT2
    h2 ab01 = bch(h2u(e01) & 0x7FFF7FFFu);
    h2 ab23 = bch(h2u(e23) & 0x7FFF7FFFu);
    p = __builtin_amdgcn_fdot2(ab01, w04a,
        __builtin_amdgcn_fdot2(ab23, w04b,
        __builtin_amdgcn_fdot2(e01, w06a,
        __builtin_amdgcn_fdot2(e23, w06b, 0.f, false), false), false), false);
#else
    {
      float e0 = (float)e01.x, e1 = (float)e01.y, e2 = (float)e23.x, e3 = (float)e23.y;
      float l0 = fmaxf(e0, 0.2f * e0), l1 = fmaxf(e1, 0.2f * e1);
      float l2 = fmaxf(e2, 0.2f * e2), l3 = fmaxf(e3, 0.2f * e3);
      p = l0 * wf.x + l1 * wf.y + l2 * wf.z + l3 * wf.w;
    }
#endif
    p += __shfl_xor(p, 1);
    p += __shfl_xor(p, 2);
    p += __shfl_xor(p, 4);
    p += __shfl_xor(p, 8);
    float ex = __expf(p);
    den += ex;
    a0 = fmaf(ex, (float)c01.x, a0);
    a1 = fmaf(ex, (float)c01.y, a1);
    a2 = fmaf(ex, (float)c23.x, a2);
    a3 = fmaf(ex, (float)c23.y, a3);
  };

  uint2 b0 = GLD(i0), b1 = GLD(i0 + 1), b2 = GLD(i0 + 2), b3 = GLD(i0 + 3);
  for (int i = i0; i < end; i += 4) {
    uint2 c0 = b0, c1 = b1, c2 = b2, c3 = b3;
    b0 = GLD(i + 4); b1 = GLD(i + 5); b2 = GLD(i + 6); b3 = GLD(i + 7);
    PROC(c0);
    if (i + 1 < end) PROC(c1);
    if (i + 2 < end) PROC(c2);
    if (i + 3 < end) PROC(c3);
  }

  float inv = 1.f / den;
  if (CONCAT) {
    float4 bb = *(const float4*)&bias[lane * 4];
    ushort4 o;
    o.x = f2h(a0 * inv + bb.x); o.y = f2h(a1 * inv + bb.y);
    o.z = f2h(a2 * inv + bb.z); o.w = f2h(a3 * inv + bb.w);
    *(ushort4*)&((unsigned short*)outv)[(size_t)d * 256 + lane * 4] = o;
  } else {
    float v0 = a0 * inv, v1 = a1 * inv, v2 = a2 * inv, v3 = a3 * inv;
    v0 += __shfl_xor(v0, 16); v0 += __shfl_xor(v0, 32);
    v1 += __shfl_xor(v1, 16); v1 += __shfl_xor(v1, 32);
    v2 += __shfl_xor(v2, 16); v2 += __shfl_xor(v2, 32);
    v3 += __shfl_xor(v3, 16); v3 += __shfl_xor(v3, 32);
    if (lane < 16) {
      float4 bb = *(const float4*)&bias[lane * 4];
      *(float4*)&((float*)outv)[(size_t)d * 64 + lane * 4] =
          make_float4(0.25f * v0 + bb.x, 0.25f * v1 + bb.y,
                      0.25f * v2 + bb.z, 0.25f * v3 + bb.w);
    }
  }
}

// column sums/sumsq over h[N,256] f16, LDS-reduced, 8 atomics per 64 lanes
__global__ __launch_bounds__(256) void bn_stats(const unsigned short* __restrict__ h,
                                                float* __restrict__ sums, int N) {
  __shared__ float4 rs[4][64], rq[4][64];
  int lane = threadIdx.x & 63;
  int rg = threadIdx.x >> 6;
  int c4 = lane * 4;
  float s0 = 0, s1 = 0, s2 = 0, s3 = 0, q0 = 0, q1 = 0, q2 = 0, q3 = 0;
  for (int r = blockIdx.x * 4 + rg; r < N; r += gridDim.x * 4) {
    uint2 v = *(const uint2*)&h[(size_t)r * 256 + c4];
    h2 a = bch(v.x), b = bch(v.y);
    float f0 = (float)a.x, f1 = (float)a.y, f2 = (float)b.x, f3 = (float)b.y;
    s0 += f0; q0 += f0 * f0;
    s1 += f1; q1 += f1 * f1;
    s2 += f2; q2 += f2 * f2;
    s3 += f3; q3 += f3 * f3;
  }
  rs[rg][lane] = make_float4(s0, s1, s2, s3);
  rq[rg][lane] = make_float4(q0, q1, q2, q3);
  __syncthreads();
  if (rg == 0) {
    float4 S = rs[0][lane], Q = rq[0][lane];
#pragma unroll
    for (int g = 1; g < 4; ++g) {
      float4 t = rs[g][lane]; S.x += t.x; S.y += t.y; S.z += t.z; S.w += t.w;
      float4 u = rq[g][lane]; Q.x += u.x; Q.y += u.y; Q.z += u.z; Q.w += u.w;
    }
    atomicAdd(&sums[c4 + 0], S.x); atomicAdd(&sums[c4 + 1], S.y);
    atomicAdd(&sums[c4 + 2], S.z); atomicAdd(&sums[c4 + 3], S.w);
    atomicAdd(&sums[256 + c4 + 0], Q.x); atomicAdd(&sums[256 + c4 + 1], Q.y);
    atomicAdd(&sums[256 + c4 + 2], Q.z); atomicAdd(&sums[256 + c4 + 3], Q.w);
  }
}

// per-channel scale/shift from sums
__global__ void bn_coef(const float* __restrict__ sums, const float* __restrict__ g,
                        const float* __restrict__ be, float* __restrict__ coef, int N) {
  int c = threadIdx.x;
  float inv_n = 1.f / (float)N;
  float mu = sums[c] * inv_n;
  float var = sums[256 + c] * inv_n - mu * mu;
  float sc = g[c] * rsqrtf(var + EPSBN);
  coef[c] = sc;
  coef[256 + c] = be[c] - mu * sc;
}

// h = relu(h*scale+shift), f16 in-place, 8 elems/thread
__global__ void bn_apply_relu(unsigned short* __restrict__ h, const float* __restrict__ coef,
                              int N) {
  int i = blockIdx.x * 256 + threadIdx.x;
  if (i >= N * 32) return;
  int base = i * 8, c = base & 255;
  uint4 v = *(const uint4*)&h[base];
  h2 p0 = bch(v.x), p1 = bch(v.y), p2 = bch(v.z), p3 = bch(v.w);
  float4 sA = *(const float4*)&coef[c];
  float4 sB = *(const float4*)&coef[c + 4];
  float4 hA = *(const float4*)&coef[256 + c];
  float4 hB = *(const float4*)&coef[256 + c + 4];
  float r0 = fmaf((float)p0.x, sA.x, hA.x); r0 = r0 > 0.f ? r0 : 0.f;
  float r1 = fmaf((float)p0.y, sA.y, hA.y); r1 = r1 > 0.f ? r1 : 0.f;
  float r2 = fmaf((float)p1.x, sA.z, hA.z); r2 = r2 > 0.f ? r2 : 0.f;
  float r3 = fmaf((float)p1.y, sA.w, hA.w); r3 = r3 > 0.f ? r3 : 0.f;
  float r4 = fmaf((float)p2.x, sB.x, hB.x); r4 = r4 > 0.f ? r4 : 0.f;
  float r5 = fmaf((float)p2.y, sB.y, hB.y); r5 = r5 > 0.f ? r5 : 0.f;
  float r6 = fmaf((float)p3.x, sB.z, hB.z); r6 = r6 > 0.f ? r6 : 0.f;
  float r7 = fmaf((float)p3.y, sB.w, hB.w); r7 = r7 > 0.f ? r7 : 0.f;
  uint4 o;
  o.x = (unsigned)f2h(r0) | ((unsigned)f2h(r1) << 16);
  o.y = (unsigned)f2h(r2) | ((unsigned)f2h(r3) << 16);
  o.z = (unsigned)f2h(r4) | ((unsigned)f2h(r5) << 16);
  o.w = (unsigned)f2h(r6) | ((unsigned)f2h(r7) << 16);
  *(uint4*)&h[base] = o;
}

// column stats over o[:, :32], coalesced float4 reads + LDS reduce
__global__ __launch_bounds__(256) void bn2_stats(const float* __restrict__ o,
                                                 float* __restrict__ sums, int N) {
  __shared__ float4 lsum[256], lqum[256];
  int t = threadIdx.x;
  int q = t & 7, rs = t >> 3;  // colquad 0..7, row-slot 0..31
  float4 S = {0, 0, 0, 0}, Q = {0, 0, 0, 0};
  for (int r = blockIdx.x * 32 + rs; r < N; r += gridDim.x * 32) {
    float4 v = *(const float4*)&o[(size_t)r * 64 + q * 4];
    S.x += v.x; Q.x += v.x * v.x;
    S.y += v.y; Q.y += v.y * v.y;
    S.z += v.z; Q.z += v.z * v.z;
    S.w += v.w; Q.w += v.w * v.w;
  }
  lsum[t] = S; lqum[t] = Q;
  __syncthreads();
  if (t < 8) {
    float4 Sa = lsum[t], Qa = lqum[t];
    for (int k = 1; k < 32; ++k) {
      float4 a = lsum[t + 8 * k], b = lqum[t + 8 * k];
      Sa.x += a.x; Sa.y += a.y; Sa.z += a.z; Sa.w += a.w;
      Qa.x += b.x; Qa.y += b.y; Qa.z += b.z; Qa.w += b.w;
    }
    atomicAdd(&sums[t * 4 + 0], Sa.x); atomicAdd(&sums[t * 4 + 1], Sa.y);
    atomicAdd(&sums[t * 4 + 2], Sa.z); atomicAdd(&sums[t * 4 + 3], Sa.w);
    atomicAdd(&sums[32 + t * 4 + 0], Qa.x); atomicAdd(&sums[32 + t * 4 + 1], Qa.y);
    atomicAdd(&sums[32 + t * 4 + 2], Qa.z); atomicAdd(&sums[32 + t * 4 + 3], Qa.w);
  }
}

// row-parallel: lanes 0-31 -> z_mu, lanes 32-63 -> sigmoid. Coalesced reads.
__global__ void write_out(const float* __restrict__ o, const float* __restrict__ sums,
                          float* __restrict__ out, int N) {
  int t = threadIdx.x;
  int n = blockIdx.x * 4 + (t >> 6);
  if (n >= N) return;
  int lane = t & 63;
  float v = o[(size_t)n * 64 + lane];
  if (lane < 32) {
    float inv_n = 1.f / (float)N;
    float mu = sums[lane] * inv_n;
    float var = sums[32 + lane] * inv_n - mu * mu;
    out[(size_t)n * 32 + lane] = (v - mu) * rsqrtf(var + EPSBN);
  } else {
    out[(size_t)N * 32 + (size_t)n * 32 + (lane - 32)] = 1.f / (1.f + __expf(-v));
  }
}

extern "C" void kernel_launch(void* const* d_in, const int* in_sizes, int n_in,
                              void* d_out, int out_size, void* d_ws, size_t ws_size,
                              hipStream_t stream) {
  const float* x    = (const float*)d_in[0];
  const int*   ei   = (const int*)d_in[1];
  const float* W1l  = (const float*)d_in[2];
  const float* W1r  = (const float*)d_in[3];
  const float* att1 = (const float*)d_in[4];
  const float* b1   = (const float*)d_in[5];
  const float* g1   = (const float*)d_in[6];
  const float* be1  = (const float*)d_in[7];
  const float* W2l  = (const float*)d_in[8];
  const float* W2r  = (const float*)d_in[9];
  const float* att2 = (const float*)d_in[10];
  const float* b2   = (const float*)d_in[11];
  float* out = (float*)d_out;

  const int N = in_sizes[0] / 256;   // 50000
  const int E = in_sizes[1] / 2;     // 800000
  const int Etot = E + N;
  const int Npad = ((N + 127) / 128) * 128;

  char* ws = (char*)d_ws;
  unsigned short* xh  = (unsigned short*)ws; ws += (size_t)Npad * 256 * 2;  // x f16
  unsigned short* hb  = (unsigned short*)ws; ws += (size_t)Npad * 256 * 2;  // h1 f16
  unsigned short* AB  = (unsigned short*)ws; ws += (size_t)Npad * 512 * 2;  // [xl|xr] f16
  unsigned short* Wt1 = (unsigned short*)ws; ws += (size_t)512 * 256 * 2;
  unsigned short* Wt2 = (unsigned short*)ws; ws += (size_t)512 * 256 * 2;
  float* o    = (float*)ws;  ws += (size_t)N * 64 * 4;
  int* rowptr = (int*)ws;    ws += (size_t)(N + 1) * 4;
  int* cnt    = (int*)ws;    ws += (size_t)N * 4;
  int* srcs   = (int*)ws;    ws += (size_t)Etot * 4;
  float* sums1 = (float*)ws; ws += 512 * 4;
  float* sums2 = (float*)ws; ws += 64 * 4;
  float* coef1 = (float*)ws; ws += 512 * 4;

  dim3 gemmGrid(Npad / 128, 4);
  int dstBlocks = (N + 3) / 4;
  int n4x = N * 64;
  int prepTotal = n4x + 131072 + 131072 + Etot;

  hipMemsetAsync(cnt, 0, (size_t)N * 4, stream);
  hipMemsetAsync(sums1, 0, 512 * 4, stream);
  hipMemsetAsync(sums2, 0, 64 * 4, stream);
  prep<<<(prepTotal + 255) / 256, 256, 0, stream>>>(x, W1l, W1r, W2l, W2r, ei,
                                                    xh, Wt1, Wt2, cnt, n4x, Etot, E);
  scan_block<<<1, 1024, 0, stream>>>(cnt, rowptr, N, Etot);
  hipMemsetAsync(cnt, 0, (size_t)N * 4, stream);
  scatter_src<<<(Etot + 255) / 256, 256, 0, stream>>>(ei, rowptr, cnt, srcs, Etot, E);

  // ---- conv1 ----
  gemm_dual<<<gemmGrid, 256, 0, stream>>>(xh, Wt1, AB, N);
  gat_fused<1><<<dstBlocks, 256, 0, stream>>>(AB, att1, b1, rowptr, srcs, hb, N);
  bn_stats<<<512, 256, 0, stream>>>(hb, sums1, N);
  bn_coef<<<1, 256, 0, stream>>>(sums1, g1, be1, coef1, N);
  bn_apply_relu<<<(N * 32 + 255) / 256, 256, 0, stream>>>(hb, coef1, N);

  // ---- conv2 ----
  gemm_dual<<<gemmGrid, 256, 0, stream>>>(hb, Wt2, AB, N);
  gat_fused<0><<<dstBlocks, 256, 0, stream>>>(AB, att2, b2, rowptr, srcs, o, N);
  bn2_stats<<<128, 256, 0, stream>>>(o, sums2, N);
  write_out<<<dstBlocks, 256, 0, stream>>>(o, sums2, out, N);
}

// Round 7
// 517.029 us; speedup vs baseline: 1.4014x; 1.1805x over previous
//
#include <hip/hip_runtime.h>
#include <math.h>

#define EPSBN 1e-5f

typedef __attribute__((ext_vector_type(8))) short short8;
typedef __attribute__((ext_vector_type(8))) _Float16 f16x8;
typedef __attribute__((ext_vector_type(2))) _Float16 h2;
typedef __attribute__((ext_vector_type(4))) float f32x4;

#if defined(__has_builtin)
#if __has_builtin(__builtin_amdgcn_fdot2)
#define HAVE_FDOT2 1
#endif
#endif

__device__ __forceinline__ unsigned short f2h(float f) {
  _Float16 h = (_Float16)f;
  return __builtin_bit_cast(unsigned short, h);
}
__device__ __forceinline__ h2 bch(unsigned u) { return __builtin_bit_cast(h2, u); }
__device__ __forceinline__ unsigned h2u(h2 v) { return __builtin_bit_cast(unsigned, v); }
// LDS XOR swizzle (involution on byte bits 4-5 <- bits 7-8) -> 2 lanes/bank
__device__ __forceinline__ int swz(int b) { return b ^ (((b >> 7) & 3) << 4); }

// ---------------------------------------------------------------------------
// dual GEMM: C[M,512] = A[M,256] @ [Wl | Wr]  (f16 in, f32 acc, f16 out)
// Wt pre-transposed: Wt[n][k]. 128x128 tile, 4 waves, BK=32, f16 MFMA.
// Swapped-operand MFMA (mfma(B,A) -> D^T): thread's 4 acc elems = 4 consecutive
// cols of one row -> ushort4 packed 8B stores.
// ---------------------------------------------------------------------------
__global__ __launch_bounds__(256) void gemm_dual(const unsigned short* __restrict__ Ab,
                                                 const unsigned short* __restrict__ Wt,
                                                 unsigned short* __restrict__ C, int M) {
  __shared__ __align__(16) short As[4096];  // 8KB [128][32] f16, swizzled
  __shared__ __align__(16) short Bs[4096];
  const int tid = threadIdx.x;
  const int lane = tid & 63, w = tid >> 6;
  const int wr = w >> 1, wc = w & 1;
  const int bm = blockIdx.x * 128, bn = blockIdx.y * 128;

  const int srow = tid >> 2;
  const int scol = (tid & 3) << 4;
  const char* gA = (const char*)Ab + (size_t)(bm + srow) * 512 + scol;
  const char* gB = (const char*)Wt + (size_t)(bn + srow) * 512 + scol;
  char* wA0 = (char*)As + swz(tid * 16);
  char* wA1 = (char*)As + swz((256 + tid) * 16);
  char* wB0 = (char*)Bs + swz(tid * 16);
  char* wB1 = (char*)Bs + swz((256 + tid) * 16);

  int aoff[4], boff[4];
#pragma unroll
  for (int i = 0; i < 4; ++i) {
    aoff[i] = swz(((wr * 64 + i * 16 + (lane & 15)) << 6) + ((lane >> 4) << 4));
    boff[i] = swz(((wc * 64 + i * 16 + (lane & 15)) << 6) + ((lane >> 4) << 4));
  }

  f32x4 acc[4][4] = {};
  short8 ra0 = *(const short8*)(gA);
  short8 ra1 = *(const short8*)(gA + 64 * 512);
  short8 rb0 = *(const short8*)(gB);
  short8 rb1 = *(const short8*)(gB + 64 * 512);

  for (int ks = 0; ks < 8; ++ks) {
    *(short8*)wA0 = ra0; *(short8*)wA1 = ra1;
    *(short8*)wB0 = rb0; *(short8*)wB1 = rb1;
    __syncthreads();
    if (ks < 7) {
      int off = (ks + 1) * 64;
      ra0 = *(const short8*)(gA + off);
      ra1 = *(const short8*)(gA + 64 * 512 + off);
      rb0 = *(const short8*)(gB + off);
      rb1 = *(const short8*)(gB + 64 * 512 + off);
    }
    short8 af[4], bfr[4];
#pragma unroll
    for (int i = 0; i < 4; ++i) af[i] = *(const short8*)((const char*)As + aoff[i]);
#pragma unroll
    for (int i = 0; i < 4; ++i) bfr[i] = *(const short8*)((const char*)Bs + boff[i]);
#pragma unroll
    for (int mr = 0; mr < 4; ++mr)
#pragma unroll
      for (int nc = 0; nc < 4; ++nc)
        acc[mr][nc] = __builtin_amdgcn_mfma_f32_16x16x32_f16(
            __builtin_bit_cast(f16x8, bfr[nc]), __builtin_bit_cast(f16x8, af[mr]),
            acc[mr][nc], 0, 0, 0);  // swapped: D^T layout
    __syncthreads();
  }

  // D^T: row = lane&15 (+m base), col = (lane>>4)*4 + j (+n base)
#pragma unroll
  for (int mr = 0; mr < 4; ++mr) {
    int row = bm + wr * 64 + mr * 16 + (lane & 15);
    if (row < M) {
#pragma unroll
      for (int nc = 0; nc < 4; ++nc) {
        int col = bn + wc * 64 + nc * 16 + ((lane >> 4) << 2);
        ushort4 o;
        o.x = f2h(acc[mr][nc][0]); o.y = f2h(acc[mr][nc][1]);
        o.z = f2h(acc[mr][nc][2]); o.w = f2h(acc[mr][nc][3]);
        *(ushort4*)&C[(size_t)row * 512 + col] = o;
      }
    }
  }
}

// ---------------------------------------------------------------------------
// prep: f32->f16 convert of x, Wt1/Wt2 build (transpose+cvt), dst histogram
// ---------------------------------------------------------------------------
__global__ void prep(const float* __restrict__ x, const float* __restrict__ W1l,
                     const float* __restrict__ W1r, const float* __restrict__ W2l,
                     const float* __restrict__ W2r, const int* __restrict__ ei,
                     unsigned short* __restrict__ xh, unsigned short* __restrict__ Wt1,
                     unsigned short* __restrict__ Wt2, int* __restrict__ cnt,
                     int n4x, int Etot, int E) {
  int t = blockIdx.x * 256 + threadIdx.x;
  if (t < n4x) {
    float4 v = *(const float4*)&x[(size_t)t * 4];
    ushort4 o;
    o.x = f2h(v.x); o.y = f2h(v.y); o.z = f2h(v.z); o.w = f2h(v.w);
    *(ushort4*)&xh[(size_t)t * 4] = o;
    return;
  }
  t -= n4x;
  if (t < 131072) {
    int n = t >> 8, k = t & 255;
    const float* W = (n < 256) ? W1l : W1r;
    Wt1[t] = f2h(W[k * 256 + (n & 255)]);
    return;
  }
  t -= 131072;
  if (t < 131072) {
    int n = t >> 8, k = t & 255;
    const float* W = (n < 256) ? W2l : W2r;
    Wt2[t] = f2h(W[k * 256 + (n & 255)]);
    return;
  }
  t -= 131072;
  if (t < Etot) {
    int d = (t < E) ? ei[E + t] : t - E;
    atomicAdd(&cnt[d], 1);
  }
}

// ---------------------------------------------------------------------------
// hierarchical exclusive scan of cnt[N] -> rowptr[N] (3 kernels, coalesced)
// ---------------------------------------------------------------------------
__global__ __launch_bounds__(256) void scan_partial(const int* __restrict__ cnt,
                                                    int* __restrict__ bsum, int N) {
  __shared__ int red[256];
  int t = threadIdx.x;
  int i = blockIdx.x * 1024 + t * 4;
  int s = 0;
  if (i + 3 < N) {
    int4 v = *(const int4*)&cnt[i];
    s = v.x + v.y + v.z + v.w;
  } else {
    for (int k = 0; k < 4; ++k)
      if (i + k < N) s += cnt[i + k];
  }
  red[t] = s;
  __syncthreads();
  for (int off = 128; off > 0; off >>= 1) {
    if (t < off) red[t] += red[t + off];
    __syncthreads();
  }
  if (t == 0) bsum[blockIdx.x] = red[0];
}

// exclusive scan of bsum[nb] (nb <= 64), one wave; also rowptr[N] = Etot
__global__ void scan_bsums(const int* __restrict__ bsum, int* __restrict__ boff,
                           int* __restrict__ rowptr, int nb, int N, int Etot) {
  int t = threadIdx.x;  // 64
  int v = (t < nb) ? bsum[t] : 0;
  int x = v;
  for (int off = 1; off < 64; off <<= 1) {
    int y = __shfl_up(x, off);
    if (t >= off) x += y;
  }
  if (t < nb) boff[t] = x - v;  // exclusive
  if (t == 0) rowptr[N] = Etot;
}

// block-local exclusive scan + base; coalesced rowptr write; zeroes cnt
__global__ __launch_bounds__(256) void scan_final(int* __restrict__ cnt,
                                                  const int* __restrict__ boff,
                                                  int* __restrict__ rowptr, int N) {
  __shared__ int red[256];
  int t = threadIdx.x;
  int i = blockIdx.x * 1024 + t * 4;
  int c0 = 0, c1 = 0, c2 = 0, c3 = 0;
  if (i + 3 < N) {
    int4 v = *(const int4*)&cnt[i];
    c0 = v.x; c1 = v.y; c2 = v.z; c3 = v.w;
    *(int4*)&cnt[i] = make_int4(0, 0, 0, 0);  // reset for scatter pass
  } else {
    if (i + 0 < N) { c0 = cnt[i + 0]; cnt[i + 0] = 0; }
    if (i + 1 < N) { c1 = cnt[i + 1]; cnt[i + 1] = 0; }
    if (i + 2 < N) { c2 = cnt[i + 2]; cnt[i + 2] = 0; }
    if (i + 3 < N) { c3 = cnt[i + 3]; cnt[i + 3] = 0; }
  }
  int s = c0 + c1 + c2 + c3;
  red[t] = s;
  __syncthreads();
  for (int off = 1; off < 256; off <<= 1) {
    int y = (t >= off) ? red[t - off] : 0;
    __syncthreads();
    red[t] += y;
    __syncthreads();
  }
  int excl = red[t] - s + boff[blockIdx.x];
  if (i + 3 < N) {
    *(int4*)&rowptr[i] = make_int4(excl, excl + c0, excl + c0 + c1, excl + c0 + c1 + c2);
  } else {
    if (i + 0 < N) rowptr[i + 0] = excl;
    if (i + 1 < N) rowptr[i + 1] = excl + c0;
    if (i + 2 < N) rowptr[i + 2] = excl + c0 + c1;
    if (i + 3 < N) rowptr[i + 3] = excl + c0 + c1 + c2;
  }
}

__global__ void scatter_src(const int* __restrict__ ei, const int* __restrict__ rowptr,
                            int* __restrict__ cur, int* __restrict__ srcs,
                            int Etot, int E) {
  int e = blockIdx.x * 256 + threadIdx.x;
  if (e >= Etot) return;
  int s, d;
  if (e < E) { s = ei[e]; d = ei[E + e]; } else { s = e - E; d = s; }
  int pos = rowptr[d] + atomicAdd(&cur[d], 1);
  srcs[pos] = s;
}

// ---------------------------------------------------------------------------
// Fused GATv2: one wave per dst, raw-exp softmax (scores bounded), f16 gathers,
// 4-deep edge prefetch pipeline (gather latency hiding).
// xlr[N][512] f16: cols 0..255 xl, 256..511 xr. lane l -> head l>>4, ch l*4..+3
// leaky_relu(x) = 0.6x + 0.4|x|;  score = e.(0.6w) + |e|.(0.4w)
// ---------------------------------------------------------------------------
template <int CONCAT>
__global__ __launch_bounds__(256) void gat_fused(const unsigned short* __restrict__ xlr,
                                                 const float* __restrict__ att,
                                                 const float* __restrict__ bias,
                                                 const int* __restrict__ rowptr,
                                                 const int* __restrict__ srcs,
                                                 void* __restrict__ outv, int N) {
  int d = (blockIdx.x << 2) + (threadIdx.x >> 6);
  if (d >= N) return;
  int lane = threadIdx.x & 63;
  uint2 ub = *(const uint2*)&xlr[(size_t)d * 512 + 256 + lane * 4];
  h2 xb01 = bch(ub.x), xb23 = bch(ub.y);
  float4 wf = *(const float4*)&att[lane * 4];  // (l>>4)*64+(l&15)*4 == l*4
  h2 w06a = {(_Float16)(0.6f * wf.x), (_Float16)(0.6f * wf.y)};
  h2 w06b = {(_Float16)(0.6f * wf.z), (_Float16)(0.6f * wf.w)};
  h2 w04a = {(_Float16)(0.4f * wf.x), (_Float16)(0.4f * wf.y)};
  h2 w04b = {(_Float16)(0.4f * wf.z), (_Float16)(0.4f * wf.w)};
  int i0 = rowptr[d], end = rowptr[d + 1];
  int eM1 = end - 1;
  float den = 0.f, a0 = 0.f, a1 = 0.f, a2 = 0.f, a3 = 0.f;

  auto GLD = [&](int j) -> uint2 {
    int jj = min(j, eM1);
    return *(const uint2*)&xlr[(size_t)srcs[jj] * 512 + lane * 4];
  };
  auto PROC = [&](uint2 cur) {
    h2 c01 = bch(cur.x), c23 = bch(cur.y);
    h2 e01 = c01 + xb01, e23 = c23 + xb23;
    float p;
#ifdef HAVE_FDOT2
    h2 ab01 = bch(h2u(e01) & 0x7FFF7FFFu);
    h2 ab23 = bch(h2u(e23) & 0x7FFF7FFFu);
    p = __builtin_amdgcn_fdot2(ab01, w04a,
        __builtin_amdgcn_fdot2(ab23, w04b,
        __builtin_amdgcn_fdot2(e01, w06a,
        __builtin_amdgcn_fdot2(e23, w06b, 0.f, false), false), false), false);
#else
    {
      float e0 = (float)e01.x, e1 = (float)e01.y, e2 = (float)e23.x, e3 = (float)e23.y;
      float l0 = fmaxf(e0, 0.2f * e0), l1 = fmaxf(e1, 0.2f * e1);
      float l2 = fmaxf(e2, 0.2f * e2), l3 = fmaxf(e3, 0.2f * e3);
      p = l0 * wf.x + l1 * wf.y + l2 * wf.z + l3 * wf.w;
    }
#endif
    p += __shfl_xor(p, 1);
    p += __shfl_xor(p, 2);
    p += __shfl_xor(p, 4);
    p += __shfl_xor(p, 8);
    float ex = __expf(p);
    den += ex;
    a0 = fmaf(ex, (float)c01.x, a0);
    a1 = fmaf(ex, (float)c01.y, a1);
    a2 = fmaf(ex, (float)c23.x, a2);
    a3 = fmaf(ex, (float)c23.y, a3);
  };

  uint2 b0 = GLD(i0), b1 = GLD(i0 + 1), b2 = GLD(i0 + 2), b3 = GLD(i0 + 3);
  for (int i = i0; i < end; i += 4) {
    uint2 c0 = b0, c1 = b1, c2 = b2, c3 = b3;
    b0 = GLD(i + 4); b1 = GLD(i + 5); b2 = GLD(i + 6); b3 = GLD(i + 7);
    PROC(c0);
    if (i + 1 < end) PROC(c1);
    if (i + 2 < end) PROC(c2);
    if (i + 3 < end) PROC(c3);
  }

  float inv = 1.f / den;
  if (CONCAT) {
    float4 bb = *(const float4*)&bias[lane * 4];
    ushort4 o;
    o.x = f2h(a0 * inv + bb.x); o.y = f2h(a1 * inv + bb.y);
    o.z = f2h(a2 * inv + bb.z); o.w = f2h(a3 * inv + bb.w);
    *(ushort4*)&((unsigned short*)outv)[(size_t)d * 256 + lane * 4] = o;
  } else {
    float v0 = a0 * inv, v1 = a1 * inv, v2 = a2 * inv, v3 = a3 * inv;
    v0 += __shfl_xor(v0, 16); v0 += __shfl_xor(v0, 32);
    v1 += __shfl_xor(v1, 16); v1 += __shfl_xor(v1, 32);
    v2 += __shfl_xor(v2, 16); v2 += __shfl_xor(v2, 32);
    v3 += __shfl_xor(v3, 16); v3 += __shfl_xor(v3, 32);
    if (lane < 16) {
      float4 bb = *(const float4*)&bias[lane * 4];
      *(float4*)&((float*)outv)[(size_t)d * 64 + lane * 4] =
          make_float4(0.25f * v0 + bb.x, 0.25f * v1 + bb.y,
                      0.25f * v2 + bb.z, 0.25f * v3 + bb.w);
    }
  }
}

// column sums/sumsq over h[N,256] f16, LDS-reduced, 8 atomics per 64 lanes
__global__ __launch_bounds__(256) void bn_stats(const unsigned short* __restrict__ h,
                                                float* __restrict__ sums, int N) {
  __shared__ float4 rs[4][64], rq[4][64];
  int lane = threadIdx.x & 63;
  int rg = threadIdx.x >> 6;
  int c4 = lane * 4;
  float s0 = 0, s1 = 0, s2 = 0, s3 = 0, q0 = 0, q1 = 0, q2 = 0, q3 = 0;
  for (int r = blockIdx.x * 4 + rg; r < N; r += gridDim.x * 4) {
    uint2 v = *(const uint2*)&h[(size_t)r * 256 + c4];
    h2 a = bch(v.x), b = bch(v.y);
    float f0 = (float)a.x, f1 = (float)a.y, f2 = (float)b.x, f3 = (float)b.y;
    s0 += f0; q0 += f0 * f0;
    s1 += f1; q1 += f1 * f1;
    s2 += f2; q2 += f2 * f2;
    s3 += f3; q3 += f3 * f3;
  }
  rs[rg][lane] = make_float4(s0, s1, s2, s3);
  rq[rg][lane] = make_float4(q0, q1, q2, q3);
  __syncthreads();
  if (rg == 0) {
    float4 S = rs[0][lane], Q = rq[0][lane];
#pragma unroll
    for (int g = 1; g < 4; ++g) {
      float4 t = rs[g][lane]; S.x += t.x; S.y += t.y; S.z += t.z; S.w += t.w;
      float4 u = rq[g][lane]; Q.x += u.x; Q.y += u.y; Q.z += u.z; Q.w += u.w;
    }
    atomicAdd(&sums[c4 + 0], S.x); atomicAdd(&sums[c4 + 1], S.y);
    atomicAdd(&sums[c4 + 2], S.z); atomicAdd(&sums[c4 + 3], S.w);
    atomicAdd(&sums[256 + c4 + 0], Q.x); atomicAdd(&sums[256 + c4 + 1], Q.y);
    atomicAdd(&sums[256 + c4 + 2], Q.z); atomicAdd(&sums[256 + c4 + 3], Q.w);
  }
}

// per-channel scale/shift from sums
__global__ void bn_coef(const float* __restrict__ sums, const float* __restrict__ g,
                        const float* __restrict__ be, float* __restrict__ coef, int N) {
  int c = threadIdx.x;
  float inv_n = 1.f / (float)N;
  float mu = sums[c] * inv_n;
  float var = sums[256 + c] * inv_n - mu * mu;
  float sc = g[c] * rsqrtf(var + EPSBN);
  coef[c] = sc;
  coef[256 + c] = be[c] - mu * sc;
}

// h = relu(h*scale+shift), f16 in-place, 8 elems/thread
__global__ void bn_apply_relu(unsigned short* __restrict__ h, const float* __restrict__ coef,
                              int N) {
  int i = blockIdx.x * 256 + threadIdx.x;
  if (i >= N * 32) return;
  int base = i * 8, c = base & 255;
  uint4 v = *(const uint4*)&h[base];
  h2 p0 = bch(v.x), p1 = bch(v.y), p2 = bch(v.z), p3 = bch(v.w);
  float4 sA = *(const float4*)&coef[c];
  float4 sB = *(const float4*)&coef[c + 4];
  float4 hA = *(const float4*)&coef[256 + c];
  float4 hB = *(const float4*)&coef[256 + c + 4];
  float r0 = fmaf((float)p0.x, sA.x, hA.x); r0 = r0 > 0.f ? r0 : 0.f;
  float r1 = fmaf((float)p0.y, sA.y, hA.y); r1 = r1 > 0.f ? r1 : 0.f;
  float r2 = fmaf((float)p1.x, sA.z, hA.z); r2 = r2 > 0.f ? r2 : 0.f;
  float r3 = fmaf((float)p1.y, sA.w, hA.w); r3 = r3 > 0.f ? r3 : 0.f;
  float r4 = fmaf((float)p2.x, sB.x, hB.x); r4 = r4 > 0.f ? r4 : 0.f;
  float r5 = fmaf((float)p2.y, sB.y, hB.y); r5 = r5 > 0.f ? r5 : 0.f;
  float r6 = fmaf((float)p3.x, sB.z, hB.z); r6 = r6 > 0.f ? r6 : 0.f;
  float r7 = fmaf((float)p3.y, sB.w, hB.w); r7 = r7 > 0.f ? r7 : 0.f;
  uint4 o;
  o.x = (unsigned)f2h(r0) | ((unsigned)f2h(r1) << 16);
  o.y = (unsigned)f2h(r2) | ((unsigned)f2h(r3) << 16);
  o.z = (unsigned)f2h(r4) | ((unsigned)f2h(r5) << 16);
  o.w = (unsigned)f2h(r6) | ((unsigned)f2h(r7) << 16);
  *(uint4*)&h[base] = o;
}

// column stats over o[:, :32], coalesced float4 reads + LDS reduce
__global__ __launch_bounds__(256) void bn2_stats(const float* __restrict__ o,
                                                 float* __restrict__ sums, int N) {
  __shared__ float4 lsum[256], lqum[256];
  int t = threadIdx.x;
  int q = t & 7, rs = t >> 3;  // colquad 0..7, row-slot 0..31
  float4 S = {0, 0, 0, 0}, Q = {0, 0, 0, 0};
  for (int r = blockIdx.x * 32 + rs; r < N; r += gridDim.x * 32) {
    float4 v = *(const float4*)&o[(size_t)r * 64 + q * 4];
    S.x += v.x; Q.x += v.x * v.x;
    S.y += v.y; Q.y += v.y * v.y;
    S.z += v.z; Q.z += v.z * v.z;
    S.w += v.w; Q.w += v.w * v.w;
  }
  lsum[t] = S; lqum[t] = Q;
  __syncthreads();
  if (t < 8) {
    float4 Sa = lsum[t], Qa = lqum[t];
    for (int k = 1; k < 32; ++k) {
      float4 a = lsum[t + 8 * k], b = lqum[t + 8 * k];
      Sa.x += a.x; Sa.y += a.y; Sa.z += a.z; Sa.w += a.w;
      Qa.x += b.x; Qa.y += b.y; Qa.z += b.z; Qa.w += b.w;
    }
    atomicAdd(&sums[t * 4 + 0], Sa.x); atomicAdd(&sums[t * 4 + 1], Sa.y);
    atomicAdd(&sums[t * 4 + 2], Sa.z); atomicAdd(&sums[t * 4 + 3], Sa.w);
    atomicAdd(&sums[32 + t * 4 + 0], Qa.x); atomicAdd(&sums[32 + t * 4 + 1], Qa.y);
    atomicAdd(&sums[32 + t * 4 + 2], Qa.z); atomicAdd(&sums[32 + t * 4 + 3], Qa.w);
  }
}

// row-parallel: lanes 0-31 -> z_mu, lanes 32-63 -> sigmoid. Coalesced reads.
__global__ void write_out(const float* __restrict__ o, const float* __restrict__ sums,
                          float* __restrict__ out, int N) {
  int t = threadIdx.x;
  int n = blockIdx.x * 4 + (t >> 6);
  if (n >= N) return;
  int lane = t & 63;
  float v = o[(size_t)n * 64 + lane];
  if (lane < 32) {
    float inv_n = 1.f / (float)N;
    float mu = sums[lane] * inv_n;
    float var = sums[32 + lane] * inv_n - mu * mu;
    out[(size_t)n * 32 + lane] = (v - mu) * rsqrtf(var + EPSBN);
  } else {
    out[(size_t)N * 32 + (size_t)n * 32 + (lane - 32)] = 1.f / (1.f + __expf(-v));
  }
}

extern "C" void kernel_launch(void* const* d_in, const int* in_sizes, int n_in,
                              void* d_out, int out_size, void* d_ws, size_t ws_size,
                              hipStream_t stream) {
  const float* x    = (const float*)d_in[0];
  const int*   ei   = (const int*)d_in[1];
  const float* W1l  = (const float*)d_in[2];
  const float* W1r  = (const float*)d_in[3];
  const float* att1 = (const float*)d_in[4];
  const float* b1   = (const float*)d_in[5];
  const float* g1   = (const float*)d_in[6];
  const float* be1  = (const float*)d_in[7];
  const float* W2l  = (const float*)d_in[8];
  const float* W2r  = (const float*)d_in[9];
  const float* att2 = (const float*)d_in[10];
  const float* b2   = (const float*)d_in[11];
  float* out = (float*)d_out;

  const int N = in_sizes[0] / 256;   // 50000
  const int E = in_sizes[1] / 2;     // 800000
  const int Etot = E + N;
  const int Npad = ((N + 127) / 128) * 128;
  const int nb = (N + 1023) / 1024;  // scan chunks

  char* ws = (char*)d_ws;
  unsigned short* xh  = (unsigned short*)ws; ws += (size_t)Npad * 256 * 2;  // x f16
  unsigned short* hb  = (unsigned short*)ws; ws += (size_t)Npad * 256 * 2;  // h1 f16
  unsigned short* AB  = (unsigned short*)ws; ws += (size_t)Npad * 512 * 2;  // [xl|xr] f16
  unsigned short* Wt1 = (unsigned short*)ws; ws += (size_t)512 * 256 * 2;
  unsigned short* Wt2 = (unsigned short*)ws; ws += (size_t)512 * 256 * 2;
  float* o    = (float*)ws;  ws += (size_t)N * 64 * 4;
  int* rowptr = (int*)ws;    ws += (size_t)(N + 1) * 4;
  int* cnt    = (int*)ws;    ws += (size_t)N * 4;
  int* srcs   = (int*)ws;    ws += (size_t)Etot * 4;
  int* bsum   = (int*)ws;    ws += 64 * 4;
  int* boff   = (int*)ws;    ws += 64 * 4;
  float* sums1 = (float*)ws; ws += 512 * 4;
  float* sums2 = (float*)ws; ws += 64 * 4;
  float* coef1 = (float*)ws; ws += 512 * 4;

  dim3 gemmGrid(Npad / 128, 4);
  int dstBlocks = (N + 3) / 4;
  int n4x = N * 64;
  int prepTotal = n4x + 131072 + 131072 + Etot;

  hipMemsetAsync(cnt, 0, (size_t)N * 4, stream);
  hipMemsetAsync(sums1, 0, 512 * 4, stream);
  hipMemsetAsync(sums2, 0, 64 * 4, stream);
  prep<<<(prepTotal + 255) / 256, 256, 0, stream>>>(x, W1l, W1r, W2l, W2r, ei,
                                                    xh, Wt1, Wt2, cnt, n4x, Etot, E);
  scan_partial<<<nb, 256, 0, stream>>>(cnt, bsum, N);
  scan_bsums<<<1, 64, 0, stream>>>(bsum, boff, rowptr, nb, N, Etot);
  scan_final<<<nb, 256, 0, stream>>>(cnt, boff, rowptr, N);  // also zeroes cnt
  scatter_src<<<(Etot + 255) / 256, 256, 0, stream>>>(ei, rowptr, cnt, srcs, Etot, E);

  // ---- conv1 ----
  gemm_dual<<<gemmGrid, 256, 0, stream>>>(xh, Wt1, AB, N);
  gat_fused<1><<<dstBlocks, 256, 0, stream>>>(AB, att1, b1, rowptr, srcs, hb, N);
  bn_stats<<<512, 256, 0, stream>>>(hb, sums1, N);
  bn_coef<<<1, 256, 0, stream>>>(sums1, g1, be1, coef1, N);
  bn_apply_relu<<<(N * 32 + 255) / 256, 256, 0, stream>>>(hb, coef1, N);

  // ---- conv2 ----
  gemm_dual<<<gemmGrid, 256, 0, stream>>>(hb, Wt2, AB, N);
  gat_fused<0><<<dstBlocks, 256, 0, stream>>>(AB, att2, b2, rowptr, srcs, o, N);
  bn2_stats<<<128, 256, 0, stream>>>(o, sums2, N);
  write_out<<<dstBlocks, 256, 0, stream>>>(o, sums2, out, N);
}